// Round 8
// baseline (1217.334 us; speedup 1.0000x reference)
//
#include <hip/hip_runtime.h>
#include <math.h>

#define LL   2048
#define BB   8
#define CC   32
#define CHH  256
#define HH   8
#define DD   6

typedef _Float16 h8 __attribute__((ext_vector_type(8)));
typedef _Float16 h4 __attribute__((ext_vector_type(4)));
typedef float f4 __attribute__((ext_vector_type(4)));
typedef float f2v __attribute__((ext_vector_type(2)));

// ---------------------------------------------------------------- encoder
__global__ __launch_bounds__(256) void k_enc(const float* __restrict__ x,
    const float* __restrict__ W, const float* __restrict__ bias,
    float* __restrict__ X) {
  int idx = blockIdx.x * 256 + threadIdx.x;          // B*32*L = 524288
  int l = idx & (LL - 1);
  int c = (idx >> 11) & 31;
  int b = idx >> 16;
  float s = bias[c];
#pragma unroll
  for (int i = 0; i < 6; ++i)
    s = fmaf(W[c * 6 + i], x[((size_t)b * 6 + i) * LL + l], s);
  X[idx] = s;
}

// ------------- fused QKV: [inline instance-norm of layer input] + pointwise
// conv + depthwise conv3/conv15 + gate + cvt + layout. The norm that was
// k_inorm #2 of the previous layer is applied at load from (Yin, stin):
// val = y*q + (beta - mean*q), q = rsqrt(var+eps)*gamma. hasn=0 for layer 0
// (raw encoder output). OOB halo stays hard zero (conv 'same' padding).
// grid (1024 = bh*16+lt, 3 z), 256 thr.
// LDS: Xt f32[32][144] @0 | o_tile 32x304B @18432 | Wt @28160 -> 32384.
__global__ __launch_bounds__(256) void k_qkv(const float* __restrict__ Xin,
    const float* __restrict__ stin, const float* __restrict__ ng,
    const float* __restrict__ nb, int hasn,
    const float* __restrict__ pwq, const float* __restrict__ pwk,
    const float* __restrict__ pwv,
    const float* __restrict__ d3q, const float* __restrict__ d15q, const float* __restrict__ gq,
    const float* __restrict__ d3k, const float* __restrict__ d15k, const float* __restrict__ gk,
    const float* __restrict__ d3v, const float* __restrict__ d15v, const float* __restrict__ gv,
    _Float16* __restrict__ Qt, _Float16* __restrict__ Kt, _Float16* __restrict__ Vt) {
  __shared__ __align__(16) char lds[32384];
  int z  = blockIdx.y;
  int bx = blockIdx.x;
  int bh = bx >> 4, lt = bx & 15, l0 = lt * 128;
  int b = bh >> 3, h = bh & 7;
  int t = threadIdx.x;
  const float* pwp  = (z == 0) ? pwq  : (z == 1) ? pwk  : pwv;
  const float* w3p  = (z == 0) ? d3q  : (z == 1) ? d3k  : d3v;
  const float* w15p = (z == 0) ? d15q : (z == 1) ? d15k : d15v;
  const float* gp   = (z == 0) ? gq   : (z == 1) ? gk   : gv;

  float* Xt = (float*)lds;                     // [32][144]
  float* Wt = (float*)(lds + 28160);           // Wt[ci*33 + och]

  // ---- stage X tile [32 ci][144 l] with inline norm (OOB zero)
  {
    int r = t >> 3, u = t & 7;
    const float* xr = Xin + ((size_t)b * CC + r) * LL;
    float scr = 1.f, shr = 0.f;
    if (hasn) {
      float s0 = stin[(b * 32 + r) * 2];
      float s1 = stin[(b * 32 + r) * 2 + 1];
      float mean = s0 * (1.f / LL);
      float var  = s1 * (1.f / LL) - mean * mean;
      float q = rsqrtf(var + 1e-5f) * ng[r];
      scr = q; shr = nb[r] - mean * q;
    }
    float* xd = Xt + r * 144;
#pragma unroll
    for (int s = u; s < 36; s += 8) {
      int ls = l0 - 8 + s * 4;
      f4 v;
      if (ls >= 0 && ls + 3 < LL) {
        v = *(const f4*)(xr + ls);
#pragma unroll
        for (int e = 0; e < 4; ++e) v[e] = fmaf(v[e], scr, shr);
      } else {
#pragma unroll
        for (int e = 0; e < 4; ++e) {
          int l = ls + e;
          v[e] = (l >= 0 && l < LL) ? fmaf(xr[l], scr, shr) : 0.f;
        }
      }
      *(f4*)(xd + s * 4) = v;
    }
  }
  // ---- stage W transposed: Wt[ci*33 + r] = pwp[(h*32+r)*32 + ci]
  {
    f4 wg = ((const f4*)(pwp + h * 1024))[t];
#pragma unroll
    for (int d2 = 0; d2 < 4; ++d2) {
      int e = t * 4 + d2;
      Wt[(e & 31) * 33 + (e >> 5)] = wg[d2];
    }
  }
  __syncthreads();

  // ---- phase 1: pointwise conv -> o_tile f16
  {
    int r = t & 31, seg = t >> 5;               // 18 l per (r,seg)
    float acc[18];
#pragma unroll
    for (int k = 0; k < 18; ++k) acc[k] = 0.f;
    for (int ci = 0; ci < 32; ++ci) {
      float w = Wt[ci * 33 + r];
      const f2v* X2 = (const f2v*)(Xt + ci * 144 + seg * 18);
#pragma unroll
      for (int m = 0; m < 9; ++m) {
        f2v xv = X2[m];
        acc[2 * m]     = fmaf(w, xv[0], acc[2 * m]);
        acc[2 * m + 1] = fmaf(w, xv[1], acc[2 * m + 1]);
      }
    }
    unsigned* orow = (unsigned*)(lds + 18432 + r * 304 + seg * 36);
#pragma unroll
    for (int m = 0; m < 9; ++m)
      orow[m] = __builtin_bit_cast(unsigned,
          __builtin_amdgcn_cvt_pkrtz(acc[2 * m], acc[2 * m + 1]));
  }
  __syncthreads();

  // ---- phase 2: depthwise conv3 + conv15 + softmax gate
  int c = t & 31, cg = t >> 5;
  float wv[32];
  {
    const h8* wp = (const h8*)(lds + 18432 + c * 304 + cg * 32);
#pragma unroll
    for (int q4 = 0; q4 < 4; ++q4) {
      h8 v = wp[q4];
#pragma unroll
      for (int e = 0; e < 8; ++e) wv[q4 * 8 + e] = (float)v[e];
    }
  }
  float r0 = gp[0], r1 = gp[1];
  float mx = fmaxf(r0, r1);
  float e0 = __expf(r0 - mx), e1 = __expf(r1 - mx);
  float gi = 1.f / (e0 + e1);
  float g0 = e0 * gi, g1 = e1 * gi;
  float sc = (z == 0) ? 0.2550765737f : 1.0f;   // C^-0.5 * log2(e) fold
  int ch = h * 32 + c;
  float w3r[3], w15r[15];
#pragma unroll
  for (int k = 0; k < 3; ++k)  w3r[k]  = w3p[ch * 3 + k];
#pragma unroll
  for (int k = 0; k < 15; ++k) w15r[k] = w15p[ch * 15 + k];

  h8 olo, ohi;
#pragma unroll
  for (int i = 0; i < 16; ++i) {
    float a = 0.f;
#pragma unroll
    for (int k = 0; k < 3; ++k) a = fmaf(w3r[k], wv[i + 7 + k], a);
    float s15 = 0.f;
#pragma unroll
    for (int k = 0; k < 15; ++k) s15 = fmaf(w15r[k], wv[i + 1 + k], s15);
    float val = (g0 * a + g1 * s15) * sc;
    if (i < 8) olo[i] = (_Float16)val; else ohi[i - 8] = (_Float16)val;
  }

  if (z == 2) {
    _Float16* dst = Vt + ((size_t)bh * 32 + c) * LL + l0 + cg * 16;
    *(h8*)dst = olo;
    *(h8*)(dst + 8) = ohi;
  } else {
    char* ot = lds;                             // reuse Xt region (dead)
#pragma unroll
    for (int i = 0; i < 16; ++i) {
      _Float16 v = (i < 8) ? olo[i] : ohi[i - 8];
      *(_Float16*)(ot + (cg * 16 + i) * 80 + c * 2) = v;
    }
    __syncthreads();
    _Float16* dst = ((z == 0) ? Qt : Kt) + ((size_t)bh * LL + l0) * 32;
    int l = t >> 1, hf = t & 1;
    uint4 a = *(uint4*)(ot + l * 80 + hf * 32);
    uint4 b2 = *(uint4*)(ot + l * 80 + hf * 32 + 16);
    *(uint4*)(dst + (size_t)l * 32 + hf * 16) = a;
    *(uint4*)(dst + (size_t)l * 32 + hf * 16 + 8) = b2;
  }
}

// ------------------------------------------------ MFMA flash attention (f16)
// (unchanged from R4/R6: 16x64 grid, 8 waves, key-split, dbuf LDS, native
// exp2, permlane PV fragment, in-LDS merge.)
__global__ __launch_bounds__(512, 2) void k_attn(
    const _Float16* __restrict__ Qt, const _Float16* __restrict__ Kt,
    const _Float16* __restrict__ Vt, _Float16* __restrict__ AO) {
  __shared__ __align__(16) char lds[38912];
  const int tid  = threadIdx.x;
  const int lane = tid & 63;
  const int w    = tid >> 6;                   // 0..7
  const int seg  = w >> 2;                     // 0..1: key segment
  const int wq   = w & 3;                      // q sub-block within 128
  const int g    = lane >> 4;
  const int ln   = lane & 15;
  const int h2c  = (wq >> 1) * 2;
  const int qb   = blockIdx.x;                 // 0..15
  const int bh   = blockIdx.y;                 // 0..63
  const _Float16* Qg = Qt + ((size_t)bh * LL + qb * 128) * 32;
  const _Float16* Kg = Kt + ((size_t)bh * LL + seg * 1024) * 32;
  const _Float16* Vg = Vt + (size_t)bh * 32 * LL + seg * 1024;

  h8 qf[2];
#pragma unroll
  for (int nt = 0; nt < 2; ++nt)
    qf[nt] = *(const h8*)(Qg + (size_t)(wq * 32 + nt * 16 + ln) * 32 + g * 8);

  h8 ones;
#pragma unroll
  for (int j = 0; j < 8; ++j) ones[j] = (_Float16)1.0f;

  char* kb = lds + seg * 5120;                 // + p*10240
  char* vb = lds + 20480 + seg * 4608;         // + p*9216

  uint4 stg0, stg1;
  if ((wq & 1) == 0) {
    const uint4* gk = (const uint4*)Kg;
    stg0 = gk[h2c * 64 + lane];
    stg1 = gk[(h2c + 1) * 64 + lane];
    *(uint4*)(kb + (h2c * 16 + (lane >> 2)) * 80 + (lane & 3) * 16) = stg0;
    *(uint4*)(kb + ((h2c + 1) * 16 + (lane >> 2)) * 80 + (lane & 3) * 16) = stg1;
  } else {
    int c0 = h2c * 8 + (lane >> 3);
    stg0 = *(const uint4*)(Vg + (size_t)c0 * LL + (lane & 7) * 8);
    stg1 = *(const uint4*)(Vg + (size_t)(c0 + 8) * LL + (lane & 7) * 8);
    *(uint4*)(vb + c0 * 144 + (lane & 7) * 16) = stg0;
    *(uint4*)(vb + (c0 + 8) * 144 + (lane & 7) * 16) = stg1;
  }
  __syncthreads();

  f4 o[2][2];
#pragma unroll
  for (int ct = 0; ct < 2; ++ct)
#pragma unroll
    for (int nt = 0; nt < 2; ++nt) o[ct][nt] = (f4){0.f, 0.f, 0.f, 0.f};
  f4 sacc[2];
#pragma unroll
  for (int nt = 0; nt < 2; ++nt) sacc[nt] = (f4){0.f, 0.f, 0.f, 0.f};

  for (int it = 0; it < 16; ++it) {
    int pp = it & 1;
    char* kbc = kb + pp * 10240;
    char* vbc = vb + pp * 9216;
    if (it < 15) {
      int k0n = (it + 1) * 64;
      if ((wq & 1) == 0) {
        const uint4* gk = (const uint4*)(Kg + (size_t)k0n * 32);
        stg0 = gk[h2c * 64 + lane];
        stg1 = gk[(h2c + 1) * 64 + lane];
      } else {
        int c0 = h2c * 8 + (lane >> 3);
        stg0 = *(const uint4*)(Vg + (size_t)c0 * LL + k0n + (lane & 7) * 8);
        stg1 = *(const uint4*)(Vg + (size_t)(c0 + 8) * LL + k0n + (lane & 7) * 8);
      }
    }
#pragma unroll
    for (int chunk = 0; chunk < 2; ++chunk) {
      unsigned pa[2][2], pb[2][2];
#pragma unroll
      for (int mt2 = 0; mt2 < 2; ++mt2) {
        h8 kf = *(const h8*)(kbc + ((chunk * 2 + mt2) * 16 + ln) * 80 + g * 16);
#pragma unroll
        for (int nt = 0; nt < 2; ++nt) {
          f4 z = {0.f, 0.f, 0.f, 0.f};
          f4 s = __builtin_amdgcn_mfma_f32_16x16x32_f16(kf, qf[nt], z, 0, 0, 0);
          float p0 = __builtin_amdgcn_exp2f(s[0]);
          float p1 = __builtin_amdgcn_exp2f(s[1]);
          float p2 = __builtin_amdgcn_exp2f(s[2]);
          float p3 = __builtin_amdgcn_exp2f(s[3]);
          unsigned lo = __builtin_bit_cast(unsigned,
              __builtin_amdgcn_cvt_pkrtz(p0, p1));
          unsigned hi = __builtin_bit_cast(unsigned,
              __builtin_amdgcn_cvt_pkrtz(p2, p3));
          if (mt2 == 0) { pa[nt][0] = lo; pa[nt][1] = hi; }
          else          { pb[nt][0] = lo; pb[nt][1] = hi; }
        }
      }
      h8 vf[2];
#pragma unroll
      for (int ct = 0; ct < 2; ++ct)
        vf[ct] = *(const h8*)(vbc + (ct * 16 + ln) * 144 + chunk * 64 + g * 16);
#pragma unroll
      for (int nt = 0; nt < 2; ++nt) {
        unsigned w0 = pa[nt][0], w1 = pa[nt][1];
        unsigned w2 = pb[nt][0], w3 = pb[nt][1];
        asm("v_permlane32_swap_b32 %0, %1" : "+v"(w0), "+v"(w2));
        asm("v_permlane16_swap_b32 %0, %1" : "+v"(w0), "+v"(w2));
        asm("v_permlane32_swap_b32 %0, %1" : "+v"(w1), "+v"(w3));
        asm("v_permlane16_swap_b32 %0, %1" : "+v"(w1), "+v"(w3));
        uint4 pw4; pw4.x = w0; pw4.y = w1; pw4.z = w2; pw4.w = w3;
        h8 pf = __builtin_bit_cast(h8, pw4);
        sacc[nt] = __builtin_amdgcn_mfma_f32_16x16x32_f16(ones, pf, sacc[nt], 0, 0, 0);
        o[0][nt] = __builtin_amdgcn_mfma_f32_16x16x32_f16(vf[0], pf, o[0][nt], 0, 0, 0);
        o[1][nt] = __builtin_amdgcn_mfma_f32_16x16x32_f16(vf[1], pf, o[1][nt], 0, 0, 0);
      }
    }
    if (it < 15) {
      char* kbn = kb + (pp ^ 1) * 10240;
      char* vbn = vb + (pp ^ 1) * 9216;
      if ((wq & 1) == 0) {
        *(uint4*)(kbn + (h2c * 16 + (lane >> 2)) * 80 + (lane & 3) * 16) = stg0;
        *(uint4*)(kbn + ((h2c + 1) * 16 + (lane >> 2)) * 80 + (lane & 3) * 16) = stg1;
      } else {
        int c0 = h2c * 8 + (lane >> 3);
        *(uint4*)(vbn + c0 * 144 + (lane & 7) * 16) = stg0;
        *(uint4*)(vbn + (c0 + 8) * 144 + (lane & 7) * 16) = stg1;
      }
    }
    __syncthreads();
  }

  if (seg == 1) {
    char* eo = lds + wq * 9216 + lane * 144;
#pragma unroll
    for (int nt = 0; nt < 2; ++nt)
#pragma unroll
      for (int ct = 0; ct < 2; ++ct)
        *(f4*)(eo + (nt * 2 + ct) * 16) = o[ct][nt];
    f4 sv;
    sv[0] = sacc[0][0]; sv[1] = sacc[1][0];
    sv[2] = 0.f; sv[3] = 0.f;
    *(f4*)(eo + 64) = sv;
  }
  __syncthreads();
  if (seg == 0) {
    const char* po = lds + wq * 9216 + lane * 144;
    f4 s1v = *(const f4*)(po + 64);
    _Float16* out = AO + (size_t)bh * (32 * LL);
#pragma unroll
    for (int nt = 0; nt < 2; ++nt) {
      float inv = 1.f / (sacc[nt][0] + s1v[nt]);
      int qg = qb * 128 + wq * 32 + nt * 16 + ln;
#pragma unroll
      for (int ct = 0; ct < 2; ++ct) {
        f4 o1 = *(const f4*)(po + (nt * 2 + ct) * 16);
#pragma unroll
        for (int r = 0; r < 4; ++r)
          out[(size_t)(ct * 16 + g * 4 + r) * LL + qg] =
              (_Float16)((o[ct][nt][r] + o1[r]) * inv);
      }
    }
  }
}

// -------- uni GEMM [32,256] f16-in + bias + residual (inline norm of prev
// layer output) -> Y1 raw + atomic per-row stats (Σ, Σ²) for norm1.
// grid 512 (8b x 32lt x 2half), 64 l per block, cc-split 4.
__global__ __launch_bounds__(256) void k_uni_res(const _Float16* __restrict__ AO,
    const float* __restrict__ W, const float* __restrict__ bias,
    const float* __restrict__ Yin, const float* __restrict__ stin,
    const float* __restrict__ png, const float* __restrict__ pnb, int hasn,
    float* __restrict__ Y, float* __restrict__ stout) {
  __shared__ float ps[3][64 * 17];
  int t    = threadIdx.x;
  int li   = t & 63;
  int cg   = t >> 6;                            // 0..3: cc quarter
  int bx   = blockIdx.x;                        // 512 blocks
  int lt   = bx & 31;
  int half = (bx >> 5) & 1;
  int b    = bx >> 6;
  int l    = lt * 64 + li;
  const _Float16* ap = AO + (size_t)b * CHH * LL + cg * 64 * (size_t)LL + l;
  float acc[16];
#pragma unroll
  for (int j = 0; j < 16; ++j) acc[j] = 0.f;
  for (int cc = 0; cc < 64; cc += 4) {
    float a0 = (float)ap[(size_t)(cc + 0) * LL];
    float a1 = (float)ap[(size_t)(cc + 1) * LL];
    float a2 = (float)ap[(size_t)(cc + 2) * LL];
    float a3 = (float)ap[(size_t)(cc + 3) * LL];
#pragma unroll
    for (int j = 0; j < 16; ++j) {
      const float* wr = W + (half * 16 + j) * CHH + cg * 64 + cc;
      acc[j] = fmaf(wr[0], a0, acc[j]);
      acc[j] = fmaf(wr[1], a1, acc[j]);
      acc[j] = fmaf(wr[2], a2, acc[j]);
      acc[j] = fmaf(wr[3], a3, acc[j]);
    }
  }
  if (cg) {
#pragma unroll
    for (int j = 0; j < 16; ++j) ps[cg - 1][li * 17 + j] = acc[j];
  }
  __syncthreads();
  if (!cg) {                                    // wave 0 (t = li = 0..63)
#pragma unroll
    for (int j = 0; j < 16; ++j) {
      int c = half * 16 + j;
      size_t o = ((size_t)b * CC + c) * LL + l;
      float res = Yin[o];
      if (hasn) {
        float s0 = stin[(b * 32 + c) * 2];
        float s1 = stin[(b * 32 + c) * 2 + 1];
        float mean = s0 * (1.f / LL);
        float var  = s1 * (1.f / LL) - mean * mean;
        float q = rsqrtf(var + 1e-5f) * png[c];
        res = fmaf(res, q, pnb[c] - mean * q);
      }
      float val = acc[j] + ps[0][li * 17 + j] + ps[1][li * 17 + j] +
                  ps[2][li * 17 + j] + bias[c] + res;
      Y[o] = val;
      float a = val, v2 = val * val;            // row stats (Σ, Σ²)
#pragma unroll
      for (int off = 32; off; off >>= 1) {
        a  += __shfl_down(a, off);
        v2 += __shfl_down(v2, off);
      }
      if (li == 0) {
        atomicAdd(&stout[(b * 32 + c) * 2], a);
        atomicAdd(&stout[(b * 32 + c) * 2 + 1], v2);
      }
    }
  }
}

// -------- fused FFN: inline norm1(Y1, st1) -> relu(W1 x + b1) -> W2 + b2 +
// residual -> Y2 raw + atomic stats for norm2. grid 512 (8b x 64lt), 32 l,
// og-split 8.
__global__ __launch_bounds__(256) void k_ffn(const float* __restrict__ Y1,
    const float* __restrict__ st1, const float* __restrict__ n1g,
    const float* __restrict__ n1b,
    const float* __restrict__ W1, const float* __restrict__ b1,
    const float* __restrict__ W2, const float* __restrict__ b2,
    float* __restrict__ Y2, float* __restrict__ stout) {
  __shared__ float ps[7][32 * 33];
  int bx = blockIdx.x;                          // 8b * 64lt
  int b = bx >> 6;
  int l0 = (bx & 63) * 32;
  int t = threadIdx.x;
  int li = t & 31;
  int og = t >> 5;                              // 0..7
  int l = l0 + li;
  const float* Xp = Y1 + (size_t)b * CC * LL + l;
  float xv[32];
#pragma unroll
  for (int c = 0; c < 32; ++c) {
    float s0 = st1[(b * 32 + c) * 2];
    float s1 = st1[(b * 32 + c) * 2 + 1];
    float mean = s0 * (1.f / LL);
    float var  = s1 * (1.f / LL) - mean * mean;
    float q = rsqrtf(var + 1e-5f) * n1g[c];
    xv[c] = fmaf(Xp[(size_t)c * LL], q, n1b[c] - mean * q);
  }
  float acc[32];
#pragma unroll
  for (int c = 0; c < 32; ++c) acc[c] = 0.f;
  for (int o = og * 16; o < og * 16 + 16; ++o) {
    float hs = b1[o];
#pragma unroll
    for (int c = 0; c < 32; ++c) hs = fmaf(W1[o * 32 + c], xv[c], hs);
    hs = fmaxf(hs, 0.f);
#pragma unroll
    for (int c = 0; c < 32; ++c) acc[c] = fmaf(W2[c * 128 + o], hs, acc[c]);
  }
  if (og) {
#pragma unroll
    for (int c = 0; c < 32; ++c) ps[og - 1][li * 33 + c] = acc[c];
  }
  __syncthreads();
  if (!og) {                                    // lanes 0..31 of wave 0
    float* Yp = Y2 + (size_t)b * CC * LL + l;
#pragma unroll
    for (int c = 0; c < 32; ++c) {
      float r = acc[c] + b2[c] + xv[c];
#pragma unroll
      for (int q = 0; q < 7; ++q) r += ps[q][li * 33 + c];
      Yp[(size_t)c * LL] = r;
      float a = r, v2 = r * r;                  // row stats over 32 lanes
#pragma unroll
      for (int off = 16; off; off >>= 1) {
        a  += __shfl_down(a, off, 32);
        v2 += __shfl_down(v2, off, 32);
      }
      if (li == 0) {
        atomicAdd(&stout[(b * 32 + c) * 2], a);
        atomicAdd(&stout[(b * 32 + c) * 2 + 1], v2);
      }
    }
  }
}

// ------------------------------------------------------------- classifier
// inline norm2 of final layer output.
__global__ __launch_bounds__(256) void k_cls(const float* __restrict__ Y2,
    const float* __restrict__ st2, const float* __restrict__ n2g,
    const float* __restrict__ n2b,
    const float* __restrict__ W, const float* __restrict__ bias,
    float* __restrict__ out) {
  int idx = blockIdx.x * 256 + threadIdx.x;
  int l = idx & (LL - 1);
  int b = idx >> 11;
  float s = bias[0];
#pragma unroll
  for (int c = 0; c < CC; ++c) {
    float s0 = st2[(b * 32 + c) * 2];
    float s1 = st2[(b * 32 + c) * 2 + 1];
    float mean = s0 * (1.f / LL);
    float var  = s1 * (1.f / LL) - mean * mean;
    float q = rsqrtf(var + 1e-5f) * n2g[c];
    float xn = fmaf(Y2[((size_t)b * CC + c) * LL + l], q, n2b[c] - mean * q);
    s = fmaf(W[c], xn, s);
  }
  out[idx] = 1.f / (1.f + __expf(-s));
}

// ------------------------------------------------------------------ launch
extern "C" void kernel_launch(void* const* d_in, const int* in_sizes, int n_in,
                              void* d_out, int out_size, void* d_ws,
                              size_t ws_size, hipStream_t stream) {
  const float* x      = (const float*)d_in[0];
  const float* enc_W  = (const float*)d_in[1];
  const float* enc_b  = (const float*)d_in[2];
  const float* pw_q   = (const float*)d_in[3];
  const float* dw3_q  = (const float*)d_in[4];
  const float* dw15_q = (const float*)d_in[5];
  const float* gate_q = (const float*)d_in[6];
  const float* pw_k   = (const float*)d_in[7];
  const float* dw3_k  = (const float*)d_in[8];
  const float* dw15_k = (const float*)d_in[9];
  const float* gate_k = (const float*)d_in[10];
  const float* pw_v   = (const float*)d_in[11];
  const float* dw3_v  = (const float*)d_in[12];
  const float* dw15_v = (const float*)d_in[13];
  const float* gate_v = (const float*)d_in[14];
  const float* uni_W  = (const float*)d_in[15];
  const float* uni_b  = (const float*)d_in[16];
  const float* n1_g   = (const float*)d_in[17];
  const float* n1_b   = (const float*)d_in[18];
  const float* n2_g   = (const float*)d_in[19];
  const float* n2_b   = (const float*)d_in[20];
  const float* ffn_W1 = (const float*)d_in[21];
  const float* ffn_b1 = (const float*)d_in[22];
  const float* ffn_W2 = (const float*)d_in[23];
  const float* ffn_b2 = (const float*)d_in[24];
  const float* cls_W  = (const float*)d_in[25];
  const float* cls_b  = (const float*)d_in[26];

  float* ws = (float*)d_ws;
  float* X0  = ws;                             // [B,32,L] fp32 enc out
  float* Y1  = ws + 524288;                    // [B,32,L] fp32 pre-norm1
  _Float16* AO = (_Float16*)(ws + 1048576);    // [B,256,L] f16 attn out
  float* Y2  = ws + 3145728;                   // [B,32,L] fp32 pre-norm2
  _Float16* Qt = (_Float16*)(ws + 9437184);    // [64bh][L][32c] f16
  _Float16* Kt = (_Float16*)(ws + 11534336);   // [64bh][L][32c] f16
  _Float16* Vt = (_Float16*)(ws + 13631488);   // [64bh][32c][L] f16
  float* st1 = ws + 15728640;                  // [6][8][32][2] f32
  float* st2 = st1 + 3072;                     // [6][8][32][2] f32

  hipMemsetAsync(st1, 0, 6144 * sizeof(float), stream);

  k_enc<<<2048, 256, 0, stream>>>(x, enc_W, enc_b, X0);

  for (int d = 0; d < DD; ++d) {
    const float* Ain  = (d == 0) ? X0 : Y2;
    const float* stA  = (d == 0) ? nullptr : st2 + (d - 1) * 512;
    const float* g2   = (d == 0) ? n2_g : n2_g + (d - 1) * CC;
    const float* b2p  = (d == 0) ? n2_b : n2_b + (d - 1) * CC;
    int hasn = (d != 0);
    k_qkv<<<dim3(1024, 3), 256, 0, stream>>>(Ain, stA, g2, b2p, hasn,
        pw_q + d * CHH * CC, pw_k + d * CHH * CC, pw_v + d * CHH * CC,
        dw3_q + d * CHH * 3, dw15_q + d * CHH * 15, gate_q + d * 2,
        dw3_k + d * CHH * 3, dw15_k + d * CHH * 15, gate_k + d * 2,
        dw3_v + d * CHH * 3, dw15_v + d * CHH * 15, gate_v + d * 2,
        Qt, Kt, Vt);
    k_attn<<<dim3(16, 64), 512, 0, stream>>>(Qt, Kt, Vt, AO);
    k_uni_res<<<512, 256, 0, stream>>>(AO, uni_W + d * CC * CHH,
        uni_b + d * CC, Ain, stA, g2, b2p, hasn, Y1, st1 + d * 512);
    k_ffn<<<512, 256, 0, stream>>>(Y1, st1 + d * 512, n1_g + d * CC,
        n1_b + d * CC, ffn_W1 + d * 128 * CC, ffn_b1 + d * 128,
        ffn_W2 + d * CC * 128, ffn_b2 + d * CC, Y2, st2 + d * 512);
  }

  k_cls<<<64, 256, 0, stream>>>(Y2, st2 + 5 * 512, n2_g + 5 * CC,
                                n2_b + 5 * CC, cls_W, cls_b, (float*)d_out);
}

// Round 9
// 1013.023 us; speedup vs baseline: 1.2017x; 1.2017x over previous
//
#include <hip/hip_runtime.h>
#include <math.h>

#define LL   2048
#define BB   8
#define CC   32
#define CHH  256
#define HH   8
#define DD   6

typedef _Float16 h8 __attribute__((ext_vector_type(8)));
typedef _Float16 h4 __attribute__((ext_vector_type(4)));
typedef float f4 __attribute__((ext_vector_type(4)));
typedef float f2v __attribute__((ext_vector_type(2)));

// ---------------------------------------------------------------- encoder
__global__ __launch_bounds__(256) void k_enc(const float* __restrict__ x,
    const float* __restrict__ W, const float* __restrict__ bias,
    float* __restrict__ X) {
  int idx = blockIdx.x * 256 + threadIdx.x;          // B*32*L = 524288
  int l = idx & (LL - 1);
  int c = (idx >> 11) & 31;
  int b = idx >> 16;
  float s = bias[c];
#pragma unroll
  for (int i = 0; i < 6; ++i)
    s = fmaf(W[c * 6 + i], x[((size_t)b * 6 + i) * LL + l], s);
  X[idx] = s;
}

// ------------- fused QKV: pointwise conv + depthwise conv3/conv15 + gate +
// cvt + layout (R6-verified form). grid (1024 = bh*16+lt, 3 z), 256 thr.
// LDS: Xt f32[32][144] @0 | o_tile 32x304B @18432 | Wt @28160 -> 32384.
__global__ __launch_bounds__(256) void k_qkv(const float* __restrict__ X,
    const float* __restrict__ pwq, const float* __restrict__ pwk,
    const float* __restrict__ pwv,
    const float* __restrict__ d3q, const float* __restrict__ d15q, const float* __restrict__ gq,
    const float* __restrict__ d3k, const float* __restrict__ d15k, const float* __restrict__ gk,
    const float* __restrict__ d3v, const float* __restrict__ d15v, const float* __restrict__ gv,
    _Float16* __restrict__ Qt, _Float16* __restrict__ Kt, _Float16* __restrict__ Vt) {
  __shared__ __align__(16) char lds[32384];
  int z  = blockIdx.y;
  int bx = blockIdx.x;
  int bh = bx >> 4, lt = bx & 15, l0 = lt * 128;
  int b = bh >> 3, h = bh & 7;
  int t = threadIdx.x;
  const float* pwp  = (z == 0) ? pwq  : (z == 1) ? pwk  : pwv;
  const float* w3p  = (z == 0) ? d3q  : (z == 1) ? d3k  : d3v;
  const float* w15p = (z == 0) ? d15q : (z == 1) ? d15k : d15v;
  const float* gp   = (z == 0) ? gq   : (z == 1) ? gk   : gv;

  float* Xt = (float*)lds;                     // [32][144]
  float* Wt = (float*)(lds + 28160);           // Wt[ci*33 + och]

  // ---- stage X tile [32 ci][144 l] (l = l0-8 .. l0+135, OOB zero)
  {
    int r = t >> 3, u = t & 7;
    const float* xr = X + ((size_t)b * CC + r) * LL;
    float* xd = Xt + r * 144;
#pragma unroll
    for (int s = u; s < 36; s += 8) {
      int ls = l0 - 8 + s * 4;
      f4 v;
      if (ls >= 0 && ls + 3 < LL) {
        v = *(const f4*)(xr + ls);
      } else {
#pragma unroll
        for (int e = 0; e < 4; ++e) {
          int l = ls + e;
          v[e] = (l >= 0 && l < LL) ? xr[l] : 0.f;
        }
      }
      *(f4*)(xd + s * 4) = v;
    }
  }
  // ---- stage W transposed: Wt[ci*33 + r] = pwp[(h*32+r)*32 + ci]
  {
    f4 wg = ((const f4*)(pwp + h * 1024))[t];
#pragma unroll
    for (int d2 = 0; d2 < 4; ++d2) {
      int e = t * 4 + d2;
      Wt[(e & 31) * 33 + (e >> 5)] = wg[d2];
    }
  }
  __syncthreads();

  // ---- phase 1: pointwise conv -> o_tile f16
  {
    int r = t & 31, seg = t >> 5;               // 18 l per (r,seg)
    float acc[18];
#pragma unroll
    for (int k = 0; k < 18; ++k) acc[k] = 0.f;
    for (int ci = 0; ci < 32; ++ci) {
      float w = Wt[ci * 33 + r];
      const f2v* X2 = (const f2v*)(Xt + ci * 144 + seg * 18);
#pragma unroll
      for (int m = 0; m < 9; ++m) {
        f2v xv = X2[m];
        acc[2 * m]     = fmaf(w, xv[0], acc[2 * m]);
        acc[2 * m + 1] = fmaf(w, xv[1], acc[2 * m + 1]);
      }
    }
    unsigned* orow = (unsigned*)(lds + 18432 + r * 304 + seg * 36);
#pragma unroll
    for (int m = 0; m < 9; ++m)
      orow[m] = __builtin_bit_cast(unsigned,
          __builtin_amdgcn_cvt_pkrtz(acc[2 * m], acc[2 * m + 1]));
  }
  __syncthreads();

  // ---- phase 2: depthwise conv3 + conv15 + softmax gate
  int c = t & 31, cg = t >> 5;
  float wv[32];
  {
    const h8* wp = (const h8*)(lds + 18432 + c * 304 + cg * 32);
#pragma unroll
    for (int q4 = 0; q4 < 4; ++q4) {
      h8 v = wp[q4];
#pragma unroll
      for (int e = 0; e < 8; ++e) wv[q4 * 8 + e] = (float)v[e];
    }
  }
  float r0 = gp[0], r1 = gp[1];
  float mx = fmaxf(r0, r1);
  float e0 = __expf(r0 - mx), e1 = __expf(r1 - mx);
  float gi = 1.f / (e0 + e1);
  float g0 = e0 * gi, g1 = e1 * gi;
  float sc = (z == 0) ? 0.2550765737f : 1.0f;   // C^-0.5 * log2(e) fold
  int ch = h * 32 + c;
  float w3r[3], w15r[15];
#pragma unroll
  for (int k = 0; k < 3; ++k)  w3r[k]  = w3p[ch * 3 + k];
#pragma unroll
  for (int k = 0; k < 15; ++k) w15r[k] = w15p[ch * 15 + k];

  h8 olo, ohi;
#pragma unroll
  for (int i = 0; i < 16; ++i) {
    float a = 0.f;
#pragma unroll
    for (int k = 0; k < 3; ++k) a = fmaf(w3r[k], wv[i + 7 + k], a);
    float s15 = 0.f;
#pragma unroll
    for (int k = 0; k < 15; ++k) s15 = fmaf(w15r[k], wv[i + 1 + k], s15);
    float val = (g0 * a + g1 * s15) * sc;
    if (i < 8) olo[i] = (_Float16)val; else ohi[i - 8] = (_Float16)val;
  }

  if (z == 2) {
    _Float16* dst = Vt + ((size_t)bh * 32 + c) * LL + l0 + cg * 16;
    *(h8*)dst = olo;
    *(h8*)(dst + 8) = ohi;
  } else {
    char* ot = lds;                             // reuse Xt region (dead)
#pragma unroll
    for (int i = 0; i < 16; ++i) {
      _Float16 v = (i < 8) ? olo[i] : ohi[i - 8];
      *(_Float16*)(ot + (cg * 16 + i) * 80 + c * 2) = v;
    }
    __syncthreads();
    _Float16* dst = ((z == 0) ? Qt : Kt) + ((size_t)bh * LL + l0) * 32;
    int l = t >> 1, hf = t & 1;
    uint4 a = *(uint4*)(ot + l * 80 + hf * 32);
    uint4 b2 = *(uint4*)(ot + l * 80 + hf * 32 + 16);
    *(uint4*)(dst + (size_t)l * 32 + hf * 16) = a;
    *(uint4*)(dst + (size_t)l * 32 + hf * 16 + 8) = b2;
  }
}

// ------------------------------------------------ MFMA flash attention (f16)
// (unchanged R4/R6 form: 16x64 grid, 8 waves, key-split, dbuf LDS, native
// exp2, permlane PV fragment, in-LDS merge.)
__global__ __launch_bounds__(512, 2) void k_attn(
    const _Float16* __restrict__ Qt, const _Float16* __restrict__ Kt,
    const _Float16* __restrict__ Vt, _Float16* __restrict__ AO) {
  __shared__ __align__(16) char lds[38912];
  const int tid  = threadIdx.x;
  const int lane = tid & 63;
  const int w    = tid >> 6;                   // 0..7
  const int seg  = w >> 2;                     // 0..1: key segment
  const int wq   = w & 3;                      // q sub-block within 128
  const int g    = lane >> 4;
  const int ln   = lane & 15;
  const int h2c  = (wq >> 1) * 2;
  const int qb   = blockIdx.x;                 // 0..15
  const int bh   = blockIdx.y;                 // 0..63
  const _Float16* Qg = Qt + ((size_t)bh * LL + qb * 128) * 32;
  const _Float16* Kg = Kt + ((size_t)bh * LL + seg * 1024) * 32;
  const _Float16* Vg = Vt + (size_t)bh * 32 * LL + seg * 1024;

  h8 qf[2];
#pragma unroll
  for (int nt = 0; nt < 2; ++nt)
    qf[nt] = *(const h8*)(Qg + (size_t)(wq * 32 + nt * 16 + ln) * 32 + g * 8);

  h8 ones;
#pragma unroll
  for (int j = 0; j < 8; ++j) ones[j] = (_Float16)1.0f;

  char* kb = lds + seg * 5120;                 // + p*10240
  char* vb = lds + 20480 + seg * 4608;         // + p*9216

  uint4 stg0, stg1;
  if ((wq & 1) == 0) {
    const uint4* gk = (const uint4*)Kg;
    stg0 = gk[h2c * 64 + lane];
    stg1 = gk[(h2c + 1) * 64 + lane];
    *(uint4*)(kb + (h2c * 16 + (lane >> 2)) * 80 + (lane & 3) * 16) = stg0;
    *(uint4*)(kb + ((h2c + 1) * 16 + (lane >> 2)) * 80 + (lane & 3) * 16) = stg1;
  } else {
    int c0 = h2c * 8 + (lane >> 3);
    stg0 = *(const uint4*)(Vg + (size_t)c0 * LL + (lane & 7) * 8);
    stg1 = *(const uint4*)(Vg + (size_t)(c0 + 8) * LL + (lane & 7) * 8);
    *(uint4*)(vb + c0 * 144 + (lane & 7) * 16) = stg0;
    *(uint4*)(vb + (c0 + 8) * 144 + (lane & 7) * 16) = stg1;
  }
  __syncthreads();

  f4 o[2][2];
#pragma unroll
  for (int ct = 0; ct < 2; ++ct)
#pragma unroll
    for (int nt = 0; nt < 2; ++nt) o[ct][nt] = (f4){0.f, 0.f, 0.f, 0.f};
  f4 sacc[2];
#pragma unroll
  for (int nt = 0; nt < 2; ++nt) sacc[nt] = (f4){0.f, 0.f, 0.f, 0.f};

  for (int it = 0; it < 16; ++it) {
    int pp = it & 1;
    char* kbc = kb + pp * 10240;
    char* vbc = vb + pp * 9216;
    if (it < 15) {
      int k0n = (it + 1) * 64;
      if ((wq & 1) == 0) {
        const uint4* gk = (const uint4*)(Kg + (size_t)k0n * 32);
        stg0 = gk[h2c * 64 + lane];
        stg1 = gk[(h2c + 1) * 64 + lane];
      } else {
        int c0 = h2c * 8 + (lane >> 3);
        stg0 = *(const uint4*)(Vg + (size_t)c0 * LL + k0n + (lane & 7) * 8);
        stg1 = *(const uint4*)(Vg + (size_t)(c0 + 8) * LL + k0n + (lane & 7) * 8);
      }
    }
#pragma unroll
    for (int chunk = 0; chunk < 2; ++chunk) {
      unsigned pa[2][2], pb[2][2];
#pragma unroll
      for (int mt2 = 0; mt2 < 2; ++mt2) {
        h8 kf = *(const h8*)(kbc + ((chunk * 2 + mt2) * 16 + ln) * 80 + g * 16);
#pragma unroll
        for (int nt = 0; nt < 2; ++nt) {
          f4 z = {0.f, 0.f, 0.f, 0.f};
          f4 s = __builtin_amdgcn_mfma_f32_16x16x32_f16(kf, qf[nt], z, 0, 0, 0);
          float p0 = __builtin_amdgcn_exp2f(s[0]);
          float p1 = __builtin_amdgcn_exp2f(s[1]);
          float p2 = __builtin_amdgcn_exp2f(s[2]);
          float p3 = __builtin_amdgcn_exp2f(s[3]);
          unsigned lo = __builtin_bit_cast(unsigned,
              __builtin_amdgcn_cvt_pkrtz(p0, p1));
          unsigned hi = __builtin_bit_cast(unsigned,
              __builtin_amdgcn_cvt_pkrtz(p2, p3));
          if (mt2 == 0) { pa[nt][0] = lo; pa[nt][1] = hi; }
          else          { pb[nt][0] = lo; pb[nt][1] = hi; }
        }
      }
      h8 vf[2];
#pragma unroll
      for (int ct = 0; ct < 2; ++ct)
        vf[ct] = *(const h8*)(vbc + (ct * 16 + ln) * 144 + chunk * 64 + g * 16);
#pragma unroll
      for (int nt = 0; nt < 2; ++nt) {
        unsigned w0 = pa[nt][0], w1 = pa[nt][1];
        unsigned w2 = pb[nt][0], w3 = pb[nt][1];
        asm("v_permlane32_swap_b32 %0, %1" : "+v"(w0), "+v"(w2));
        asm("v_permlane16_swap_b32 %0, %1" : "+v"(w0), "+v"(w2));
        asm("v_permlane32_swap_b32 %0, %1" : "+v"(w1), "+v"(w3));
        asm("v_permlane16_swap_b32 %0, %1" : "+v"(w1), "+v"(w3));
        uint4 pw4; pw4.x = w0; pw4.y = w1; pw4.z = w2; pw4.w = w3;
        h8 pf = __builtin_bit_cast(h8, pw4);
        sacc[nt] = __builtin_amdgcn_mfma_f32_16x16x32_f16(ones, pf, sacc[nt], 0, 0, 0);
        o[0][nt] = __builtin_amdgcn_mfma_f32_16x16x32_f16(vf[0], pf, o[0][nt], 0, 0, 0);
        o[1][nt] = __builtin_amdgcn_mfma_f32_16x16x32_f16(vf[1], pf, o[1][nt], 0, 0, 0);
      }
    }
    if (it < 15) {
      char* kbn = kb + (pp ^ 1) * 10240;
      char* vbn = vb + (pp ^ 1) * 9216;
      if ((wq & 1) == 0) {
        *(uint4*)(kbn + (h2c * 16 + (lane >> 2)) * 80 + (lane & 3) * 16) = stg0;
        *(uint4*)(kbn + ((h2c + 1) * 16 + (lane >> 2)) * 80 + (lane & 3) * 16) = stg1;
      } else {
        int c0 = h2c * 8 + (lane >> 3);
        *(uint4*)(vbn + c0 * 144 + (lane & 7) * 16) = stg0;
        *(uint4*)(vbn + (c0 + 8) * 144 + (lane & 7) * 16) = stg1;
      }
    }
    __syncthreads();
  }

  if (seg == 1) {
    char* eo = lds + wq * 9216 + lane * 144;
#pragma unroll
    for (int nt = 0; nt < 2; ++nt)
#pragma unroll
      for (int ct = 0; ct < 2; ++ct)
        *(f4*)(eo + (nt * 2 + ct) * 16) = o[ct][nt];
    f4 sv;
    sv[0] = sacc[0][0]; sv[1] = sacc[1][0];
    sv[2] = 0.f; sv[3] = 0.f;
    *(f4*)(eo + 64) = sv;
  }
  __syncthreads();
  if (seg == 0) {
    const char* po = lds + wq * 9216 + lane * 144;
    f4 s1v = *(const f4*)(po + 64);
    _Float16* out = AO + (size_t)bh * (32 * LL);
#pragma unroll
    for (int nt = 0; nt < 2; ++nt) {
      float inv = 1.f / (sacc[nt][0] + s1v[nt]);
      int qg = qb * 128 + wq * 32 + nt * 16 + ln;
#pragma unroll
      for (int ct = 0; ct < 2; ++ct) {
        f4 o1 = *(const f4*)(po + (nt * 2 + ct) * 16);
#pragma unroll
        for (int r = 0; r < 4; ++r)
          out[(size_t)(ct * 16 + g * 4 + r) * LL + qg] =
              (_Float16)((o[ct][nt][r] + o1[r]) * inv);
      }
    }
  }
}

// -------- uni GEMM [32,256] f16-in + bias + residual (R6-verified form).
// grid 512 (8b x 32lt x 2half), 64 l per block, cc-split 4.
__global__ __launch_bounds__(256) void k_uni_res(const _Float16* __restrict__ AO,
    const float* __restrict__ W, const float* __restrict__ bias,
    const float* __restrict__ Xin, float* __restrict__ Y) {
  __shared__ float ps[3][64 * 17];
  int t    = threadIdx.x;
  int li   = t & 63;
  int cg   = t >> 6;                            // 0..3: cc quarter
  int bx   = blockIdx.x;                        // 512 blocks
  int lt   = bx & 31;
  int half = (bx >> 5) & 1;
  int b    = bx >> 6;
  int l    = lt * 64 + li;
  const _Float16* ap = AO + (size_t)b * CHH * LL + cg * 64 * (size_t)LL + l;
  float acc[16];
#pragma unroll
  for (int j = 0; j < 16; ++j) acc[j] = 0.f;
  for (int cc = 0; cc < 64; cc += 4) {
    float a0 = (float)ap[(size_t)(cc + 0) * LL];
    float a1 = (float)ap[(size_t)(cc + 1) * LL];
    float a2 = (float)ap[(size_t)(cc + 2) * LL];
    float a3 = (float)ap[(size_t)(cc + 3) * LL];
#pragma unroll
    for (int j = 0; j < 16; ++j) {
      const float* wr = W + (half * 16 + j) * CHH + cg * 64 + cc;
      acc[j] = fmaf(wr[0], a0, acc[j]);
      acc[j] = fmaf(wr[1], a1, acc[j]);
      acc[j] = fmaf(wr[2], a2, acc[j]);
      acc[j] = fmaf(wr[3], a3, acc[j]);
    }
  }
  if (cg) {
#pragma unroll
    for (int j = 0; j < 16; ++j) ps[cg - 1][li * 17 + j] = acc[j];
  }
  __syncthreads();
  if (!cg) {
#pragma unroll
    for (int j = 0; j < 16; ++j) {
      int c = half * 16 + j;
      size_t o = ((size_t)b * CC + c) * LL + l;
      Y[o] = acc[j] + ps[0][li * 17 + j] + ps[1][li * 17 + j] +
             ps[2][li * 17 + j] + bias[c] + Xin[o];
    }
  }
}

// ---------------------------------------------------------- instance norm
// (R6-verified form: 512 threads, 4 elems/thread.)
__global__ __launch_bounds__(512) void k_inorm(const float* __restrict__ Y,
    float* __restrict__ X, const float* __restrict__ g,
    const float* __restrict__ bt) {
  __shared__ float red[16];
  int row = blockIdx.x;
  int c = row & 31;
  const float* y = Y + (size_t)row * LL;
  float v[4];
  float s = 0.f, ss = 0.f;
#pragma unroll
  for (int i = 0; i < 4; ++i) {
    v[i] = y[threadIdx.x + 512 * i];
    s += v[i];
    ss = fmaf(v[i], v[i], ss);
  }
#pragma unroll
  for (int off = 32; off; off >>= 1) {
    s  += __shfl_down(s, off);
    ss += __shfl_down(ss, off);
  }
  int wid = threadIdx.x >> 6;
  if ((threadIdx.x & 63) == 0) { red[wid * 2] = s; red[wid * 2 + 1] = ss; }
  __syncthreads();
  if (threadIdx.x == 0) {
    float rs0 = 0.f, rs1 = 0.f;
#pragma unroll
    for (int i = 0; i < 8; ++i) { rs0 += red[i * 2]; rs1 += red[i * 2 + 1]; }
    red[0] = rs0; red[1] = rs1;
  }
  __syncthreads();
  float mean = red[0] * (1.f / LL);
  float var  = red[1] * (1.f / LL) - mean * mean;
  float rs = rsqrtf(var + 1e-5f) * g[c];
  float bb = bt[c];
#pragma unroll
  for (int i = 0; i < 4; ++i)
    X[(size_t)row * LL + threadIdx.x + 512 * i] = (v[i] - mean) * rs + bb;
}

// -------- fused FFN v3: relu(W1 x + b1) -> W2 + b2 + residual.
// R9 ILP restructure (R8 data: k_ffn ~67us at VALUBusy 7.9% = 92% idle,
// stalled on the 32-deep dependent fmaf chain per hidden unit):
//  * 2 hidden units (o, o+1) in flight per iteration
//  * each as a 4-wide partial-sum f4 (chain depth 32 -> 8, 8 indep chains)
//  * f4 vector loads of W1 rows, f2v loads of W2 (o,o+1) pairs
// fp32 reassociation error ~1e-6 << 0.00195 budget.
// grid 512 (8b x 64lt), 32 l per block, og-split 8 (16 o each).
__global__ __launch_bounds__(256) void k_ffn(const float* __restrict__ X,
    const float* __restrict__ W1, const float* __restrict__ b1,
    const float* __restrict__ W2, const float* __restrict__ b2,
    float* __restrict__ Y) {
  __shared__ float ps[7][32 * 33];
  int bx = blockIdx.x;                          // 8b * 64lt
  int b = bx >> 6;
  int l0 = (bx & 63) * 32;
  int t = threadIdx.x;
  int li = t & 31;
  int og = t >> 5;                              // 0..7
  int l = l0 + li;
  const float* Xp = X + (size_t)b * CC * LL + l;
  float xv[32];
#pragma unroll
  for (int c = 0; c < 32; ++c) xv[c] = Xp[(size_t)c * LL];
  float acc[32];
#pragma unroll
  for (int c = 0; c < 32; ++c) acc[c] = 0.f;
#pragma unroll
  for (int op = 0; op < 8; ++op) {
    int o = og * 16 + op * 2;
    f4 h0 = {b1[o], 0.f, 0.f, 0.f};
    f4 h1 = {b1[o + 1], 0.f, 0.f, 0.f};
    const f4* w0 = (const f4*)(W1 + o * 32);
    const f4* w1 = (const f4*)(W1 + (o + 1) * 32);
#pragma unroll
    for (int c4 = 0; c4 < 8; ++c4) {
      f4 a0 = w0[c4], a1 = w1[c4];
      h0[0] = fmaf(a0[0], xv[c4 * 4 + 0], h0[0]);
      h0[1] = fmaf(a0[1], xv[c4 * 4 + 1], h0[1]);
      h0[2] = fmaf(a0[2], xv[c4 * 4 + 2], h0[2]);
      h0[3] = fmaf(a0[3], xv[c4 * 4 + 3], h0[3]);
      h1[0] = fmaf(a1[0], xv[c4 * 4 + 0], h1[0]);
      h1[1] = fmaf(a1[1], xv[c4 * 4 + 1], h1[1]);
      h1[2] = fmaf(a1[2], xv[c4 * 4 + 2], h1[2]);
      h1[3] = fmaf(a1[3], xv[c4 * 4 + 3], h1[3]);
    }
    float hs0 = fmaxf((h0[0] + h0[1]) + (h0[2] + h0[3]), 0.f);
    float hs1 = fmaxf((h1[0] + h1[1]) + (h1[2] + h1[3]), 0.f);
#pragma unroll
    for (int c = 0; c < 32; ++c) {
      f2v w2 = *(const f2v*)(W2 + c * 128 + o);
      acc[c] = fmaf(w2[0], hs0, fmaf(w2[1], hs1, acc[c]));
    }
  }
  if (og) {
#pragma unroll
    for (int c = 0; c < 32; ++c) ps[og - 1][li * 33 + c] = acc[c];
  }
  __syncthreads();
  if (!og) {
    float* Yp = Y + (size_t)b * CC * LL + l;
#pragma unroll
    for (int c = 0; c < 32; ++c) {
      float r = acc[c] + b2[c] + xv[c];
#pragma unroll
      for (int q = 0; q < 7; ++q) r += ps[q][li * 33 + c];
      Yp[(size_t)c * LL] = r;
    }
  }
}

// ------------------------------------------------------------- classifier
__global__ __launch_bounds__(256) void k_cls(const float* __restrict__ X,
    const float* __restrict__ W, const float* __restrict__ bias,
    float* __restrict__ out) {
  int idx = blockIdx.x * 256 + threadIdx.x;
  int l = idx & (LL - 1);
  int b = idx >> 11;
  float s = bias[0];
#pragma unroll
  for (int c = 0; c < CC; ++c)
    s = fmaf(W[c], X[((size_t)b * CC + c) * LL + l], s);
  out[idx] = 1.f / (1.f + __expf(-s));
}

// ------------------------------------------------------------------ launch
extern "C" void kernel_launch(void* const* d_in, const int* in_sizes, int n_in,
                              void* d_out, int out_size, void* d_ws,
                              size_t ws_size, hipStream_t stream) {
  const float* x      = (const float*)d_in[0];
  const float* enc_W  = (const float*)d_in[1];
  const float* enc_b  = (const float*)d_in[2];
  const float* pw_q   = (const float*)d_in[3];
  const float* dw3_q  = (const float*)d_in[4];
  const float* dw15_q = (const float*)d_in[5];
  const float* gate_q = (const float*)d_in[6];
  const float* pw_k   = (const float*)d_in[7];
  const float* dw3_k  = (const float*)d_in[8];
  const float* dw15_k = (const float*)d_in[9];
  const float* gate_k = (const float*)d_in[10];
  const float* pw_v   = (const float*)d_in[11];
  const float* dw3_v  = (const float*)d_in[12];
  const float* dw15_v = (const float*)d_in[13];
  const float* gate_v = (const float*)d_in[14];
  const float* uni_W  = (const float*)d_in[15];
  const float* uni_b  = (const float*)d_in[16];
  const float* n1_g   = (const float*)d_in[17];
  const float* n1_b   = (const float*)d_in[18];
  const float* n2_g   = (const float*)d_in[19];
  const float* n2_b   = (const float*)d_in[20];
  const float* ffn_W1 = (const float*)d_in[21];
  const float* ffn_b1 = (const float*)d_in[22];
  const float* ffn_W2 = (const float*)d_in[23];
  const float* ffn_b2 = (const float*)d_in[24];
  const float* cls_W  = (const float*)d_in[25];
  const float* cls_b  = (const float*)d_in[26];

  float* ws = (float*)d_ws;
  float* X   = ws;                             // [B,32,L] fp32
  float* Y   = ws + 524288;                    // [B,32,L] fp32
  _Float16* AO = (_Float16*)(ws + 1048576);    // [B,256,L] f16 attn out
  _Float16* Qt = (_Float16*)(ws + 9437184);    // [64bh][L][32c] f16
  _Float16* Kt = (_Float16*)(ws + 11534336);   // [64bh][L][32c] f16
  _Float16* Vt = (_Float16*)(ws + 13631488);   // [64bh][32c][L] f16

  k_enc<<<2048, 256, 0, stream>>>(x, enc_W, enc_b, X);

  for (int d = 0; d < DD; ++d) {
    k_qkv<<<dim3(1024, 3), 256, 0, stream>>>(X,
        pw_q + d * CHH * CC, pw_k + d * CHH * CC, pw_v + d * CHH * CC,
        dw3_q + d * CHH * 3, dw15_q + d * CHH * 15, gate_q + d * 2,
        dw3_k + d * CHH * 3, dw15_k + d * CHH * 15, gate_k + d * 2,
        dw3_v + d * CHH * 3, dw15_v + d * CHH * 15, gate_v + d * 2,
        Qt, Kt, Vt);
    k_attn<<<dim3(16, 64), 512, 0, stream>>>(Qt, Kt, Vt, AO);
    k_uni_res<<<512, 256, 0, stream>>>(AO, uni_W + d * CC * CHH,
                                       uni_b + d * CC, X, Y);
    k_inorm<<<256, 512, 0, stream>>>(Y, X, n1_g + d * CC, n1_b + d * CC);
    k_ffn<<<512, 256, 0, stream>>>(X, ffn_W1 + d * 128 * CC, ffn_b1 + d * 128,
                                   ffn_W2 + d * CC * 128, ffn_b2 + d * CC, Y);
    k_inorm<<<256, 512, 0, stream>>>(Y, X, n2_g + d * CC, n2_b + d * CC);
  }

  k_cls<<<64, 256, 0, stream>>>(X, cls_W, cls_b, (float*)d_out);
}

// Round 10
// 878.796 us; speedup vs baseline: 1.3852x; 1.1527x over previous
//
#include <hip/hip_runtime.h>
#include <math.h>

#define LL   2048
#define BB   8
#define CC   32
#define CHH  256
#define HH   8
#define DD   6

typedef _Float16 h8 __attribute__((ext_vector_type(8)));
typedef _Float16 h4 __attribute__((ext_vector_type(4)));
typedef float f4 __attribute__((ext_vector_type(4)));
typedef float f2v __attribute__((ext_vector_type(2)));

// ---------------------------------------------------------------- encoder
__global__ __launch_bounds__(256) void k_enc(const float* __restrict__ x,
    const float* __restrict__ W, const float* __restrict__ bias,
    float* __restrict__ X) {
  int idx = blockIdx.x * 256 + threadIdx.x;          // B*32*L = 524288
  int l = idx & (LL - 1);
  int c = (idx >> 11) & 31;
  int b = idx >> 16;
  float s = bias[c];
#pragma unroll
  for (int i = 0; i < 6; ++i)
    s = fmaf(W[c * 6 + i], x[((size_t)b * 6 + i) * LL + l], s);
  X[idx] = s;
}

// ------------- fused QKV: pointwise conv + depthwise conv3/conv15 + gate +
// cvt + layout (R6-verified form). grid (1024 = bh*16+lt, 3 z), 256 thr.
// LDS: Xt f32[32][144] @0 | o_tile 32x304B @18432 | Wt @28160 -> 32384.
__global__ __launch_bounds__(256) void k_qkv(const float* __restrict__ X,
    const float* __restrict__ pwq, const float* __restrict__ pwk,
    const float* __restrict__ pwv,
    const float* __restrict__ d3q, const float* __restrict__ d15q, const float* __restrict__ gq,
    const float* __restrict__ d3k, const float* __restrict__ d15k, const float* __restrict__ gk,
    const float* __restrict__ d3v, const float* __restrict__ d15v, const float* __restrict__ gv,
    _Float16* __restrict__ Qt, _Float16* __restrict__ Kt, _Float16* __restrict__ Vt) {
  __shared__ __align__(16) char lds[32384];
  int z  = blockIdx.y;
  int bx = blockIdx.x;
  int bh = bx >> 4, lt = bx & 15, l0 = lt * 128;
  int b = bh >> 3, h = bh & 7;
  int t = threadIdx.x;
  const float* pwp  = (z == 0) ? pwq  : (z == 1) ? pwk  : pwv;
  const float* w3p  = (z == 0) ? d3q  : (z == 1) ? d3k  : d3v;
  const float* w15p = (z == 0) ? d15q : (z == 1) ? d15k : d15v;
  const float* gp   = (z == 0) ? gq   : (z == 1) ? gk   : gv;

  float* Xt = (float*)lds;                     // [32][144]
  float* Wt = (float*)(lds + 28160);           // Wt[ci*33 + och]

  // ---- stage X tile [32 ci][144 l] (l = l0-8 .. l0+135, OOB zero)
  {
    int r = t >> 3, u = t & 7;
    const float* xr = X + ((size_t)b * CC + r) * LL;
    float* xd = Xt + r * 144;
#pragma unroll
    for (int s = u; s < 36; s += 8) {
      int ls = l0 - 8 + s * 4;
      f4 v;
      if (ls >= 0 && ls + 3 < LL) {
        v = *(const f4*)(xr + ls);
      } else {
#pragma unroll
        for (int e = 0; e < 4; ++e) {
          int l = ls + e;
          v[e] = (l >= 0 && l < LL) ? xr[l] : 0.f;
        }
      }
      *(f4*)(xd + s * 4) = v;
    }
  }
  // ---- stage W transposed: Wt[ci*33 + r] = pwp[(h*32+r)*32 + ci]
  {
    f4 wg = ((const f4*)(pwp + h * 1024))[t];
#pragma unroll
    for (int d2 = 0; d2 < 4; ++d2) {
      int e = t * 4 + d2;
      Wt[(e & 31) * 33 + (e >> 5)] = wg[d2];
    }
  }
  __syncthreads();

  // ---- phase 1: pointwise conv -> o_tile f16
  {
    int r = t & 31, seg = t >> 5;               // 18 l per (r,seg)
    float acc[18];
#pragma unroll
    for (int k = 0; k < 18; ++k) acc[k] = 0.f;
    for (int ci = 0; ci < 32; ++ci) {
      float w = Wt[ci * 33 + r];
      const f2v* X2 = (const f2v*)(Xt + ci * 144 + seg * 18);
#pragma unroll
      for (int m = 0; m < 9; ++m) {
        f2v xv = X2[m];
        acc[2 * m]     = fmaf(w, xv[0], acc[2 * m]);
        acc[2 * m + 1] = fmaf(w, xv[1], acc[2 * m + 1]);
      }
    }
    unsigned* orow = (unsigned*)(lds + 18432 + r * 304 + seg * 36);
#pragma unroll
    for (int m = 0; m < 9; ++m)
      orow[m] = __builtin_bit_cast(unsigned,
          __builtin_amdgcn_cvt_pkrtz(acc[2 * m], acc[2 * m + 1]));
  }
  __syncthreads();

  // ---- phase 2: depthwise conv3 + conv15 + softmax gate
  int c = t & 31, cg = t >> 5;
  float wv[32];
  {
    const h8* wp = (const h8*)(lds + 18432 + c * 304 + cg * 32);
#pragma unroll
    for (int q4 = 0; q4 < 4; ++q4) {
      h8 v = wp[q4];
#pragma unroll
      for (int e = 0; e < 8; ++e) wv[q4 * 8 + e] = (float)v[e];
    }
  }
  float r0 = gp[0], r1 = gp[1];
  float mx = fmaxf(r0, r1);
  float e0 = __expf(r0 - mx), e1 = __expf(r1 - mx);
  float gi = 1.f / (e0 + e1);
  float g0 = e0 * gi, g1 = e1 * gi;
  float sc = (z == 0) ? 0.2550765737f : 1.0f;   // C^-0.5 * log2(e) fold
  int ch = h * 32 + c;
  float w3r[3], w15r[15];
#pragma unroll
  for (int k = 0; k < 3; ++k)  w3r[k]  = w3p[ch * 3 + k];
#pragma unroll
  for (int k = 0; k < 15; ++k) w15r[k] = w15p[ch * 15 + k];

  h8 olo, ohi;
#pragma unroll
  for (int i = 0; i < 16; ++i) {
    float a = 0.f;
#pragma unroll
    for (int k = 0; k < 3; ++k) a = fmaf(w3r[k], wv[i + 7 + k], a);
    float s15 = 0.f;
#pragma unroll
    for (int k = 0; k < 15; ++k) s15 = fmaf(w15r[k], wv[i + 1 + k], s15);
    float val = (g0 * a + g1 * s15) * sc;
    if (i < 8) olo[i] = (_Float16)val; else ohi[i - 8] = (_Float16)val;
  }

  if (z == 2) {
    _Float16* dst = Vt + ((size_t)bh * 32 + c) * LL + l0 + cg * 16;
    *(h8*)dst = olo;
    *(h8*)(dst + 8) = ohi;
  } else {
    char* ot = lds;                             // reuse Xt region (dead)
#pragma unroll
    for (int i = 0; i < 16; ++i) {
      _Float16 v = (i < 8) ? olo[i] : ohi[i - 8];
      *(_Float16*)(ot + (cg * 16 + i) * 80 + c * 2) = v;
    }
    __syncthreads();
    _Float16* dst = ((z == 0) ? Qt : Kt) + ((size_t)bh * LL + l0) * 32;
    int l = t >> 1, hf = t & 1;
    uint4 a = *(uint4*)(ot + l * 80 + hf * 32);
    uint4 b2 = *(uint4*)(ot + l * 80 + hf * 32 + 16);
    *(uint4*)(dst + (size_t)l * 32 + hf * 16) = a;
    *(uint4*)(dst + (size_t)l * 32 + hf * 16 + 8) = b2;
  }
}

// ------------------------------------------------ MFMA flash attention (f16)
// (unchanged R4/R6 form: 16x64 grid, 8 waves, key-split, dbuf LDS, native
// exp2, permlane PV fragment, in-LDS merge.)
__global__ __launch_bounds__(512, 2) void k_attn(
    const _Float16* __restrict__ Qt, const _Float16* __restrict__ Kt,
    const _Float16* __restrict__ Vt, _Float16* __restrict__ AO) {
  __shared__ __align__(16) char lds[38912];
  const int tid  = threadIdx.x;
  const int lane = tid & 63;
  const int w    = tid >> 6;                   // 0..7
  const int seg  = w >> 2;                     // 0..1: key segment
  const int wq   = w & 3;                      // q sub-block within 128
  const int g    = lane >> 4;
  const int ln   = lane & 15;
  const int h2c  = (wq >> 1) * 2;
  const int qb   = blockIdx.x;                 // 0..15
  const int bh   = blockIdx.y;                 // 0..63
  const _Float16* Qg = Qt + ((size_t)bh * LL + qb * 128) * 32;
  const _Float16* Kg = Kt + ((size_t)bh * LL + seg * 1024) * 32;
  const _Float16* Vg = Vt + (size_t)bh * 32 * LL + seg * 1024;

  h8 qf[2];
#pragma unroll
  for (int nt = 0; nt < 2; ++nt)
    qf[nt] = *(const h8*)(Qg + (size_t)(wq * 32 + nt * 16 + ln) * 32 + g * 8);

  h8 ones;
#pragma unroll
  for (int j = 0; j < 8; ++j) ones[j] = (_Float16)1.0f;

  char* kb = lds + seg * 5120;                 // + p*10240
  char* vb = lds + 20480 + seg * 4608;         // + p*9216

  uint4 stg0, stg1;
  if ((wq & 1) == 0) {
    const uint4* gk = (const uint4*)Kg;
    stg0 = gk[h2c * 64 + lane];
    stg1 = gk[(h2c + 1) * 64 + lane];
    *(uint4*)(kb + (h2c * 16 + (lane >> 2)) * 80 + (lane & 3) * 16) = stg0;
    *(uint4*)(kb + ((h2c + 1) * 16 + (lane >> 2)) * 80 + (lane & 3) * 16) = stg1;
  } else {
    int c0 = h2c * 8 + (lane >> 3);
    stg0 = *(const uint4*)(Vg + (size_t)c0 * LL + (lane & 7) * 8);
    stg1 = *(const uint4*)(Vg + (size_t)(c0 + 8) * LL + (lane & 7) * 8);
    *(uint4*)(vb + c0 * 144 + (lane & 7) * 16) = stg0;
    *(uint4*)(vb + (c0 + 8) * 144 + (lane & 7) * 16) = stg1;
  }
  __syncthreads();

  f4 o[2][2];
#pragma unroll
  for (int ct = 0; ct < 2; ++ct)
#pragma unroll
    for (int nt = 0; nt < 2; ++nt) o[ct][nt] = (f4){0.f, 0.f, 0.f, 0.f};
  f4 sacc[2];
#pragma unroll
  for (int nt = 0; nt < 2; ++nt) sacc[nt] = (f4){0.f, 0.f, 0.f, 0.f};

  for (int it = 0; it < 16; ++it) {
    int pp = it & 1;
    char* kbc = kb + pp * 10240;
    char* vbc = vb + pp * 9216;
    if (it < 15) {
      int k0n = (it + 1) * 64;
      if ((wq & 1) == 0) {
        const uint4* gk = (const uint4*)(Kg + (size_t)k0n * 32);
        stg0 = gk[h2c * 64 + lane];
        stg1 = gk[(h2c + 1) * 64 + lane];
      } else {
        int c0 = h2c * 8 + (lane >> 3);
        stg0 = *(const uint4*)(Vg + (size_t)c0 * LL + k0n + (lane & 7) * 8);
        stg1 = *(const uint4*)(Vg + (size_t)(c0 + 8) * LL + k0n + (lane & 7) * 8);
      }
    }
#pragma unroll
    for (int chunk = 0; chunk < 2; ++chunk) {
      unsigned pa[2][2], pb[2][2];
#pragma unroll
      for (int mt2 = 0; mt2 < 2; ++mt2) {
        h8 kf = *(const h8*)(kbc + ((chunk * 2 + mt2) * 16 + ln) * 80 + g * 16);
#pragma unroll
        for (int nt = 0; nt < 2; ++nt) {
          f4 z = {0.f, 0.f, 0.f, 0.f};
          f4 s = __builtin_amdgcn_mfma_f32_16x16x32_f16(kf, qf[nt], z, 0, 0, 0);
          float p0 = __builtin_amdgcn_exp2f(s[0]);
          float p1 = __builtin_amdgcn_exp2f(s[1]);
          float p2 = __builtin_amdgcn_exp2f(s[2]);
          float p3 = __builtin_amdgcn_exp2f(s[3]);
          unsigned lo = __builtin_bit_cast(unsigned,
              __builtin_amdgcn_cvt_pkrtz(p0, p1));
          unsigned hi = __builtin_bit_cast(unsigned,
              __builtin_amdgcn_cvt_pkrtz(p2, p3));
          if (mt2 == 0) { pa[nt][0] = lo; pa[nt][1] = hi; }
          else          { pb[nt][0] = lo; pb[nt][1] = hi; }
        }
      }
      h8 vf[2];
#pragma unroll
      for (int ct = 0; ct < 2; ++ct)
        vf[ct] = *(const h8*)(vbc + (ct * 16 + ln) * 144 + chunk * 64 + g * 16);
#pragma unroll
      for (int nt = 0; nt < 2; ++nt) {
        unsigned w0 = pa[nt][0], w1 = pa[nt][1];
        unsigned w2 = pb[nt][0], w3 = pb[nt][1];
        asm("v_permlane32_swap_b32 %0, %1" : "+v"(w0), "+v"(w2));
        asm("v_permlane16_swap_b32 %0, %1" : "+v"(w0), "+v"(w2));
        asm("v_permlane32_swap_b32 %0, %1" : "+v"(w1), "+v"(w3));
        asm("v_permlane16_swap_b32 %0, %1" : "+v"(w1), "+v"(w3));
        uint4 pw4; pw4.x = w0; pw4.y = w1; pw4.z = w2; pw4.w = w3;
        h8 pf = __builtin_bit_cast(h8, pw4);
        sacc[nt] = __builtin_amdgcn_mfma_f32_16x16x32_f16(ones, pf, sacc[nt], 0, 0, 0);
        o[0][nt] = __builtin_amdgcn_mfma_f32_16x16x32_f16(vf[0], pf, o[0][nt], 0, 0, 0);
        o[1][nt] = __builtin_amdgcn_mfma_f32_16x16x32_f16(vf[1], pf, o[1][nt], 0, 0, 0);
      }
    }
    if (it < 15) {
      char* kbn = kb + (pp ^ 1) * 10240;
      char* vbn = vb + (pp ^ 1) * 9216;
      if ((wq & 1) == 0) {
        *(uint4*)(kbn + (h2c * 16 + (lane >> 2)) * 80 + (lane & 3) * 16) = stg0;
        *(uint4*)(kbn + ((h2c + 1) * 16 + (lane >> 2)) * 80 + (lane & 3) * 16) = stg1;
      } else {
        int c0 = h2c * 8 + (lane >> 3);
        *(uint4*)(vbn + c0 * 144 + (lane & 7) * 16) = stg0;
        *(uint4*)(vbn + (c0 + 8) * 144 + (lane & 7) * 16) = stg1;
      }
    }
    __syncthreads();
  }

  if (seg == 1) {
    char* eo = lds + wq * 9216 + lane * 144;
#pragma unroll
    for (int nt = 0; nt < 2; ++nt)
#pragma unroll
      for (int ct = 0; ct < 2; ++ct)
        *(f4*)(eo + (nt * 2 + ct) * 16) = o[ct][nt];
    f4 sv;
    sv[0] = sacc[0][0]; sv[1] = sacc[1][0];
    sv[2] = 0.f; sv[3] = 0.f;
    *(f4*)(eo + 64) = sv;
  }
  __syncthreads();
  if (seg == 0) {
    const char* po = lds + wq * 9216 + lane * 144;
    f4 s1v = *(const f4*)(po + 64);
    _Float16* out = AO + (size_t)bh * (32 * LL);
#pragma unroll
    for (int nt = 0; nt < 2; ++nt) {
      float inv = 1.f / (sacc[nt][0] + s1v[nt]);
      int qg = qb * 128 + wq * 32 + nt * 16 + ln;
#pragma unroll
      for (int ct = 0; ct < 2; ++ct) {
        f4 o1 = *(const f4*)(po + (nt * 2 + ct) * 16);
#pragma unroll
        for (int r = 0; r < 4; ++r)
          out[(size_t)(ct * 16 + g * 4 + r) * LL + qg] =
              (_Float16)((o[ct][nt][r] + o1[r]) * inv);
      }
    }
  }
}

// -------- uni GEMM [32,256] f16-in + bias + residual (R6-verified form).
// grid 512 (8b x 32lt x 2half), 64 l per block, cc-split 4.
__global__ __launch_bounds__(256) void k_uni_res(const _Float16* __restrict__ AO,
    const float* __restrict__ W, const float* __restrict__ bias,
    const float* __restrict__ Xin, float* __restrict__ Y) {
  __shared__ float ps[3][64 * 17];
  int t    = threadIdx.x;
  int li   = t & 63;
  int cg   = t >> 6;                            // 0..3: cc quarter
  int bx   = blockIdx.x;                        // 512 blocks
  int lt   = bx & 31;
  int half = (bx >> 5) & 1;
  int b    = bx >> 6;
  int l    = lt * 64 + li;
  const _Float16* ap = AO + (size_t)b * CHH * LL + cg * 64 * (size_t)LL + l;
  float acc[16];
#pragma unroll
  for (int j = 0; j < 16; ++j) acc[j] = 0.f;
  for (int cc = 0; cc < 64; cc += 4) {
    float a0 = (float)ap[(size_t)(cc + 0) * LL];
    float a1 = (float)ap[(size_t)(cc + 1) * LL];
    float a2 = (float)ap[(size_t)(cc + 2) * LL];
    float a3 = (float)ap[(size_t)(cc + 3) * LL];
#pragma unroll
    for (int j = 0; j < 16; ++j) {
      const float* wr = W + (half * 16 + j) * CHH + cg * 64 + cc;
      acc[j] = fmaf(wr[0], a0, acc[j]);
      acc[j] = fmaf(wr[1], a1, acc[j]);
      acc[j] = fmaf(wr[2], a2, acc[j]);
      acc[j] = fmaf(wr[3], a3, acc[j]);
    }
  }
  if (cg) {
#pragma unroll
    for (int j = 0; j < 16; ++j) ps[cg - 1][li * 17 + j] = acc[j];
  }
  __syncthreads();
  if (!cg) {
#pragma unroll
    for (int j = 0; j < 16; ++j) {
      int c = half * 16 + j;
      size_t o = ((size_t)b * CC + c) * LL + l;
      Y[o] = acc[j] + ps[0][li * 17 + j] + ps[1][li * 17 + j] +
             ps[2][li * 17 + j] + bias[c] + Xin[o];
    }
  }
}

// ---------------------------------------------------------- instance norm
// (R6-verified form: 512 threads, 4 elems/thread.)
__global__ __launch_bounds__(512) void k_inorm(const float* __restrict__ Y,
    float* __restrict__ X, const float* __restrict__ g,
    const float* __restrict__ bt) {
  __shared__ float red[16];
  int row = blockIdx.x;
  int c = row & 31;
  const float* y = Y + (size_t)row * LL;
  float v[4];
  float s = 0.f, ss = 0.f;
#pragma unroll
  for (int i = 0; i < 4; ++i) {
    v[i] = y[threadIdx.x + 512 * i];
    s += v[i];
    ss = fmaf(v[i], v[i], ss);
  }
#pragma unroll
  for (int off = 32; off; off >>= 1) {
    s  += __shfl_down(s, off);
    ss += __shfl_down(ss, off);
  }
  int wid = threadIdx.x >> 6;
  if ((threadIdx.x & 63) == 0) { red[wid * 2] = s; red[wid * 2 + 1] = ss; }
  __syncthreads();
  if (threadIdx.x == 0) {
    float rs0 = 0.f, rs1 = 0.f;
#pragma unroll
    for (int i = 0; i < 8; ++i) { rs0 += red[i * 2]; rs1 += red[i * 2 + 1]; }
    red[0] = rs0; red[1] = rs1;
  }
  __syncthreads();
  float mean = red[0] * (1.f / LL);
  float var  = red[1] * (1.f / LL) - mean * mean;
  float rs = rsqrtf(var + 1e-5f) * g[c];
  float bb = bt[c];
#pragma unroll
  for (int i = 0; i < 4; ++i)
    X[(size_t)row * LL + threadIdx.x + 512 * i] = (v[i] - mean) * rs + bb;
}

// -------- fused FFN v5: relu(W1 x + b1) -> W2 + b2 + residual.
// R10: LDS-stage ALL weights (W1 16KB + W2 16KB + b1) once per block with
// coalesced f4 loads — R8 counters (67us, VALUBusy 7.9%, HBM 0.8%, 97%
// stall) implicate serialized uniform weight loads (s_load + wait chains),
// not the fma chain alone. All weight reads now hit LDS (broadcast = free).
// Phase-split: all 16 hs first (4-wide partials, chain 32->8), then acc via
// f4 LDS reads. Epilogue/grid/og-split unchanged from R6 (verified 929us).
// LDS: wlds 33.3KB + ps 29.6KB = 62.8KB -> 2 blocks/CU (grid gives 2).
__global__ __launch_bounds__(256) void k_ffn(const float* __restrict__ X,
    const float* __restrict__ W1, const float* __restrict__ b1,
    const float* __restrict__ W2, const float* __restrict__ b2,
    float* __restrict__ Y) {
  __shared__ __align__(16) float wlds[8320];    // W1 @0, W2 @4096, b1 @8192
  __shared__ float ps[7][32 * 33];
  int bx = blockIdx.x;                          // 8b * 64lt
  int b = bx >> 6;
  int l0 = (bx & 63) * 32;
  int t = threadIdx.x;
  int li = t & 31;
  int og = t >> 5;                              // 0..7
  int l = l0 + li;
  // ---- stage weights to LDS (coalesced f4)
#pragma unroll
  for (int i = 0; i < 4; ++i)
    ((f4*)wlds)[t + i * 256] = ((const f4*)W1)[t + i * 256];
#pragma unroll
  for (int i = 0; i < 4; ++i)
    ((f4*)(wlds + 4096))[t + i * 256] = ((const f4*)W2)[t + i * 256];
  if (t < 32) ((f4*)(wlds + 8192))[t] = ((const f4*)b1)[t];

  const float* Xp = X + (size_t)b * CC * LL + l;
  float xv[32];
#pragma unroll
  for (int c = 0; c < 32; ++c) xv[c] = Xp[(size_t)c * LL];
  __syncthreads();

  // ---- phase A: 16 hidden units, 4-wide partial chains from LDS
  float hs[16];
#pragma unroll
  for (int op = 0; op < 16; ++op) {
    int o = og * 16 + op;
    const f4* wr = (const f4*)(wlds + o * 32);
    f4 p = {wlds[8192 + o], 0.f, 0.f, 0.f};
#pragma unroll
    for (int c4 = 0; c4 < 8; ++c4) {
      f4 a = wr[c4];
      p[0] = fmaf(a[0], xv[c4 * 4 + 0], p[0]);
      p[1] = fmaf(a[1], xv[c4 * 4 + 1], p[1]);
      p[2] = fmaf(a[2], xv[c4 * 4 + 2], p[2]);
      p[3] = fmaf(a[3], xv[c4 * 4 + 3], p[3]);
    }
    hs[op] = fmaxf((p[0] + p[1]) + (p[2] + p[3]), 0.f);
  }

  // ---- phase B: 32 outputs, f4 W2 reads from LDS
  float acc[32];
#pragma unroll
  for (int c = 0; c < 32; ++c) {
    const f4* w2r = (const f4*)(wlds + 4096 + c * 128 + og * 16);
    f4 s = {0.f, 0.f, 0.f, 0.f};
#pragma unroll
    for (int o4 = 0; o4 < 4; ++o4) {
      f4 w = w2r[o4];
      s[0] = fmaf(w[0], hs[o4 * 4 + 0], s[0]);
      s[1] = fmaf(w[1], hs[o4 * 4 + 1], s[1]);
      s[2] = fmaf(w[2], hs[o4 * 4 + 2], s[2]);
      s[3] = fmaf(w[3], hs[o4 * 4 + 3], s[3]);
    }
    acc[c] = (s[0] + s[1]) + (s[2] + s[3]);
  }

  if (og) {
#pragma unroll
    for (int c = 0; c < 32; ++c) ps[og - 1][li * 33 + c] = acc[c];
  }
  __syncthreads();
  if (!og) {
    float* Yp = Y + (size_t)b * CC * LL + l;
#pragma unroll
    for (int c = 0; c < 32; ++c) {
      float r = acc[c] + b2[c] + xv[c];
#pragma unroll
      for (int q = 0; q < 7; ++q) r += ps[q][li * 33 + c];
      Yp[(size_t)c * LL] = r;
    }
  }
}

// ------------------------------------------------------------- classifier
__global__ __launch_bounds__(256) void k_cls(const float* __restrict__ X,
    const float* __restrict__ W, const float* __restrict__ bias,
    float* __restrict__ out) {
  int idx = blockIdx.x * 256 + threadIdx.x;
  int l = idx & (LL - 1);
  int b = idx >> 11;
  float s = bias[0];
#pragma unroll
  for (int c = 0; c < CC; ++c)
    s = fmaf(W[c], X[((size_t)b * CC + c) * LL + l], s);
  out[idx] = 1.f / (1.f + __expf(-s));
}

// ------------------------------------------------------------------ launch
extern "C" void kernel_launch(void* const* d_in, const int* in_sizes, int n_in,
                              void* d_out, int out_size, void* d_ws,
                              size_t ws_size, hipStream_t stream) {
  const float* x      = (const float*)d_in[0];
  const float* enc_W  = (const float*)d_in[1];
  const float* enc_b  = (const float*)d_in[2];
  const float* pw_q   = (const float*)d_in[3];
  const float* dw3_q  = (const float*)d_in[4];
  const float* dw15_q = (const float*)d_in[5];
  const float* gate_q = (const float*)d_in[6];
  const float* pw_k   = (const float*)d_in[7];
  const float* dw3_k  = (const float*)d_in[8];
  const float* dw15_k = (const float*)d_in[9];
  const float* gate_k = (const float*)d_in[10];
  const float* pw_v   = (const float*)d_in[11];
  const float* dw3_v  = (const float*)d_in[12];
  const float* dw15_v = (const float*)d_in[13];
  const float* gate_v = (const float*)d_in[14];
  const float* uni_W  = (const float*)d_in[15];
  const float* uni_b  = (const float*)d_in[16];
  const float* n1_g   = (const float*)d_in[17];
  const float* n1_b   = (const float*)d_in[18];
  const float* n2_g   = (const float*)d_in[19];
  const float* n2_b   = (const float*)d_in[20];
  const float* ffn_W1 = (const float*)d_in[21];
  const float* ffn_b1 = (const float*)d_in[22];
  const float* ffn_W2 = (const float*)d_in[23];
  const float* ffn_b2 = (const float*)d_in[24];
  const float* cls_W  = (const float*)d_in[25];
  const float* cls_b  = (const float*)d_in[26];

  float* ws = (float*)d_ws;
  float* X   = ws;                             // [B,32,L] fp32
  float* Y   = ws + 524288;                    // [B,32,L] fp32
  _Float16* AO = (_Float16*)(ws + 1048576);    // [B,256,L] f16 attn out
  _Float16* Qt = (_Float16*)(ws + 9437184);    // [64bh][L][32c] f16
  _Float16* Kt = (_Float16*)(ws + 11534336);   // [64bh][L][32c] f16
  _Float16* Vt = (_Float16*)(ws + 13631488);   // [64bh][32c][L] f16

  k_enc<<<2048, 256, 0, stream>>>(x, enc_W, enc_b, X);

  for (int d = 0; d < DD; ++d) {
    k_qkv<<<dim3(1024, 3), 256, 0, stream>>>(X,
        pw_q + d * CHH * CC, pw_k + d * CHH * CC, pw_v + d * CHH * CC,
        dw3_q + d * CHH * 3, dw15_q + d * CHH * 15, gate_q + d * 2,
        dw3_k + d * CHH * 3, dw15_k + d * CHH * 15, gate_k + d * 2,
        dw3_v + d * CHH * 3, dw15_v + d * CHH * 15, gate_v + d * 2,
        Qt, Kt, Vt);
    k_attn<<<dim3(16, 64), 512, 0, stream>>>(Qt, Kt, Vt, AO);
    k_uni_res<<<512, 256, 0, stream>>>(AO, uni_W + d * CC * CHH,
                                       uni_b + d * CC, X, Y);
    k_inorm<<<256, 512, 0, stream>>>(Y, X, n1_g + d * CC, n1_b + d * CC);
    k_ffn<<<512, 256, 0, stream>>>(X, ffn_W1 + d * 128 * CC, ffn_b1 + d * 128,
                                   ffn_W2 + d * CC * 128, ffn_b2 + d * CC, Y);
    k_inorm<<<256, 512, 0, stream>>>(Y, X, n2_g + d * CC, n2_b + d * CC);
  }

  k_cls<<<64, 256, 0, stream>>>(X, cls_W, cls_b, (float*)d_out);
}